// Round 3
// baseline (170.569 us; speedup 1.0000x reference)
//
#include <hip/hip_runtime.h>
#include <hip/hip_bf16.h>

// TreeLSTM on MI355X — round 15: whole-forest fusion v3 (wavefront pipeline).
// Changes vs round 14 (90 us forest):
//  - d6 tiles ride inside the d7 loop (tile j in interval 2j+2): 3-4 independent
//    tiles per barrier interval; d6/d5 tail phase shrinks (16 -> 15 intervals,
//    heavy intervals carry 2-4x the independent work for the 2 waves/SIMD).
//  - ALL global x loads hoisted to interval start (covered by MFMA issue);
//    tail levels (d5..d0) prefetch ax one interval AHEAD into registers —
//    legal across lgkmcnt-only barriers (vmcnt never drained).
//  - VGPR budget intentionally spent on staging (1 block/CU is LDS-bound, so
//    anything <=256 VGPR costs nothing).

#define TS 511
#define NT 128
#define NN (NT * TS)   // 65408

typedef __attribute__((ext_vector_type(8))) short short8;
typedef __attribute__((ext_vector_type(4))) float floatx4;

#define MFMA_B16 __builtin_amdgcn_mfma_f32_16x16x32_bf16

// LDS-only barrier: LDS writes visible, global loads NOT drained.
#define BARLDS() do { \
    asm volatile("s_waitcnt lgkmcnt(0)" ::: "memory"); \
    __builtin_amdgcn_s_barrier(); \
    asm volatile("" ::: "memory"); \
} while (0)

__device__ __forceinline__ unsigned short f2b(float f) {
    return __builtin_bit_cast(unsigned short, __float2bfloat16(f));
}
__device__ __forceinline__ float b2f_u(unsigned short u) {
    unsigned v = (unsigned)u << 16;
    return __builtin_bit_cast(float, v);
}
__device__ __forceinline__ float rcp_(float x) { return __builtin_amdgcn_rcpf(x); }
__device__ __forceinline__ float sig_(float x) { return rcp_(1.0f + __expf(-x)); }
__device__ __forceinline__ float tanh_(float x) {
    float a = fabsf(x);
    float t = __expf(-2.0f * a);
    return copysignf((1.0f - t) * rcp_(1.0f + t), x);
}

// ---------------- weight packing + x conversion ----------------
__global__ void pack_b(const float* __restrict__ Wiou, const float* __restrict__ biou,
                       const float* __restrict__ Uiou, const float* __restrict__ Wf,
                       const float* __restrict__ bfv, const float* __restrict__ Uf,
                       const float* __restrict__ feat,
                       unsigned short* __restrict__ BgU, unsigned short* __restrict__ BgX,
                       float* __restrict__ bp5, unsigned short* __restrict__ xb) {
    int tid = blockIdx.x * 256 + threadIdx.x;   // 0..1308671
    if (tid < 1280) {
        int l = tid / 640, r = tid % 640, g = r >> 7, o = r & 127;
        bp5[tid] = (g < 3) ? biou[l * 384 + r] : bfv[l * 128 + o];
    }
    if (tid < 131072) {
        int l = tid >> 16, r = tid & 65535, col = r >> 7, kp = r & 127;
        float v = (col < 384) ? Uiou[(l * 384 + col) * 128 + kp]
                              : Uf[(l * 128 + (col - 384)) * 128 + kp];
        BgU[((size_t)(l * 512 + col)) * 128 + kp] = f2b(v);
    } else if (tid < 262144) {
        int e2 = tid - 131072;
        int l = e2 >> 16, r = e2 & 65535, col = r >> 7, kp = r & 127;
        float v = (col < 384) ? Wiou[(l * 384 + col) * 128 + kp]
                              : Wf[(l * 128 + (col - 384)) * 128 + kp];
        BgX[((size_t)(l * 512 + col)) * 128 + kp] = f2b(v);
    } else {
        int e = tid - 262144;                  // < 1046528, 8 elems each
        size_t base = (size_t)e * 8;
        float4 v0 = *(const float4*)(feat + base);
        float4 v1 = *(const float4*)(feat + base + 4);
        short8 r;
        r[0] = (short)f2b(v0.x); r[1] = (short)f2b(v0.y);
        r[2] = (short)f2b(v0.z); r[3] = (short)f2b(v0.w);
        r[4] = (short)f2b(v1.x); r[5] = (short)f2b(v1.y);
        r[6] = (short)f2b(v1.z); r[7] = (short)f2b(v1.w);
        *(short8*)(xb + base) = r;
    }
}

// ---------------- whole-forest kernel ----------------
// LDS (halfwords, row stride 136):
//   h-space rows 0..191: internal ring (d7:0..127, d6:128..191, d5:0..31,
//     d4:32..47, d3:48..55, d2:56..59, d1:60..61, d0:62)
//   c-space rows 0..191 @S[HC0]: same ring
//   leaf h: rows 384+b*32+r (h-space), leaf c: rows 256+b*32+r (c-space)
__global__ __launch_bounds__(512, 2) void forest(
        const unsigned short* __restrict__ xb16, const unsigned short* __restrict__ BgU,
        const unsigned short* __restrict__ BgX, const float* __restrict__ bp5,
        float* __restrict__ out) {
    __shared__ __align__(16) unsigned short S[69632];
    const int HC0 = 26112;

    const int tid = threadIdx.x;
    const int l = blockIdx.x >> 7, tree = blockIdx.x & 127;
    const int lane = tid & 63, w = tid >> 6;
    const int quad = lane >> 4, l15 = lane & 15;
    const int o = w * 16 + l15;
    const unsigned short* xb = xb16 + (size_t)tree * TS * 128;
    const unsigned short* BU = BgU + (size_t)l * 512 * 128;
    const unsigned short* BX = BgX + (size_t)l * 512 * 128;

    // resident B fragments: gates i,o,u,f (f0/f1 share Wf and Uf cols)
    short8 bU[4][4], bX[4][4];
#pragma unroll
    for (int g = 0; g < 4; g++) {
        const size_t cb = (size_t)(g * 128 + o) * 128;
#pragma unroll
        for (int kbl = 0; kbl < 4; kbl++) {
            bU[g][kbl] = *(const short8*)(BU + cb + kbl * 32 + quad * 8);
            bX[g][kbl] = *(const short8*)(BX + cb + kbl * 32 + quad * 8);
        }
    }
    float bb[5];
#pragma unroll
    for (int g = 0; g < 5; g++) bb[g] = bp5[l * 640 + g * 128 + o];

    auto ldx = [&](int heap, int kbl) -> short8 {
        return *(const short8*)(xb + (size_t)heap * 128 + kbl * 32 + quad * 8);
    };
    struct X4 { short8 a[4]; };
    auto pfx = [&](int heap) -> X4 {
        X4 r;
#pragma unroll
        for (int k = 0; k < 4; k++) r.a[k] = ldx(heap, k);
        return r;
    };

    // 16-row leaf tile from prefetched x
    auto ltile = [&](const X4& ax, int selfH, int selfC) {
        floatx4 ai = (floatx4){0.f, 0.f, 0.f, 0.f};
        floatx4 ao = ai, au = ai;
#pragma unroll
        for (int kbl = 0; kbl < 4; kbl++) {
            ai = MFMA_B16(ax.a[kbl], bX[0][kbl], ai, 0, 0, 0);
            ao = MFMA_B16(ax.a[kbl], bX[1][kbl], ao, 0, 0, 0);
            au = MFMA_B16(ax.a[kbl], bX[2][kbl], au, 0, 0, 0);
        }
#pragma unroll
        for (int r = 0; r < 4; r++) {
            int idx = quad * 4 + r;
            float iv = sig_(ai[r] + bb[0]);
            float ov = sig_(ao[r] + bb[1]);
            float uv = tanh_(au[r] + bb[2]);
            float cn = iv * uv;
            float hn = ov * tanh_(cn);
            S[(selfH + idx) * 136 + o] = f2b(hn);
            S[HC0 + (selfC + idx) * 136 + o] = f2b(cn);
        }
    };

    // 16-node internal tile from prefetched x
    auto itile = [&](const X4& ax, int chAh, int selfRB, int chRBc,
                     int nValid, bool isRoot) {
        floatx4 ai = (floatx4){0.f, 0.f, 0.f, 0.f};
        floatx4 ao = ai, au = ai, awx = ai, af0 = ai, af1 = ai;
#pragma unroll
        for (int kbl = 0; kbl < 4; kbl++) {
            short8 h0 = *(const short8*)&S[chAh * 136 + kbl * 32 + quad * 8];
            short8 h1 = *(const short8*)&S[(chAh + 1) * 136 + kbl * 32 + quad * 8];
            ai = MFMA_B16(h0, bU[0][kbl], ai, 0, 0, 0);
            ai = MFMA_B16(h1, bU[0][kbl], ai, 0, 0, 0);
            ao = MFMA_B16(h0, bU[1][kbl], ao, 0, 0, 0);
            ao = MFMA_B16(h1, bU[1][kbl], ao, 0, 0, 0);
            au = MFMA_B16(h0, bU[2][kbl], au, 0, 0, 0);
            au = MFMA_B16(h1, bU[2][kbl], au, 0, 0, 0);
            af0 = MFMA_B16(h0, bU[3][kbl], af0, 0, 0, 0);
            af1 = MFMA_B16(h1, bU[3][kbl], af1, 0, 0, 0);
            ai = MFMA_B16(ax.a[kbl], bX[0][kbl], ai, 0, 0, 0);
            ao = MFMA_B16(ax.a[kbl], bX[1][kbl], ao, 0, 0, 0);
            au = MFMA_B16(ax.a[kbl], bX[2][kbl], au, 0, 0, 0);
            awx = MFMA_B16(ax.a[kbl], bX[3][kbl], awx, 0, 0, 0);
        }
#pragma unroll
        for (int r = 0; r < 4; r++) {
            int idx = quad * 4 + r;
            if (idx < nValid) {
                float iv = sig_(ai[r] + bb[0]);
                float ov = sig_(ao[r] + bb[1]);
                float uv = tanh_(au[r] + bb[2]);
                float f0 = sig_(awx[r] + af0[r] + bb[3]);
                float f1 = sig_(awx[r] + af1[r] + bb[4]);
                float c0 = b2f_u(S[HC0 + (chRBc + 2 * idx) * 136 + o]);
                float c1 = b2f_u(S[HC0 + (chRBc + 2 * idx + 1) * 136 + o]);
                float cn = iv * uv + f0 * c0 + f1 * c1;
                float hn = ov * tanh_(cn);
                S[(selfRB + idx) * 136 + o] = f2b(hn);
                S[HC0 + (selfRB + idx) * 136 + o] = f2b(cn);
                if (isRoot) {
                    out[((size_t)l * 128 + tree) * 128 + o] = hn;
                    out[32768 + ((size_t)l * 128 + tree) * 128 + o] = cn;
                }
            }
        }
    };

    // ---- prologue: leaf pair 0 -> buf 0 ----
    {
        X4 p0 = pfx(255 + l15), p1 = pfx(271 + l15);
        ltile(p0, 384, 256);
        ltile(p1, 400, 272);
    }
    BARLDS();

    X4 axT0, axT1;   // cross-barrier tail prefetch

    // ---- intervals 0..7: d7 tile t + leaf pair t+1 + (d6 tile j at t=2j+2) ----
#pragma unroll 1
    for (int t = 0; t < 8; t++) {
        X4 lx0, lx1, axd, axe;
        // all global loads for this interval issue first
        axd = pfx(127 + t * 16 + l15);
        if (t < 7) { lx0 = pfx(287 + t * 32 + l15); lx1 = pfx(303 + t * 32 + l15); }
        const bool do6 = (t == 2) || (t == 4) || (t == 6);
        const int j = (t - 2) >> 1;
        if (do6) axe = pfx(63 + j * 16 + l15);
        if (t == 7) { axT0 = pfx(111 + l15); axT1 = pfx(31 + l15); }  // d6t3, d5t0

        const int b = t & 1, b2 = b ^ 1;
        if (t < 7) {
            ltile(lx0, 384 + b2 * 32, 256 + b2 * 32);
            ltile(lx1, 384 + b2 * 32 + 16, 256 + b2 * 32 + 16);
        }
        itile(axd, 384 + b * 32 + 2 * l15, t * 16, 256 + b * 32, 16, false);
        if (do6) itile(axe, 2 * (j * 16 + l15), 128 + j * 16, 32 * j, 16, false);
        BARLDS();
    }

    // ---- interval 8: d6 tile3 + d5 tile0 ----
    itile(axT0, 96 + 2 * l15, 176, 96, 16, false);
    itile(axT1, 128 + 2 * l15, 0, 128, 16, false);
    axT0 = pfx(47 + l15);                       // d5 tile1
    BARLDS();
    // ---- interval 9: d5 tile1 ----
    itile(axT0, 160 + 2 * l15, 16, 160, 16, false);
    axT0 = pfx(15 + l15);                       // d4
    BARLDS();
    // ---- interval 10: d4 ----
    itile(axT0, 2 * l15, 32, 0, 16, false);
    { int rl = (l15 < 7) ? l15 : 7; axT0 = pfx(7 + rl); }   // d3
    BARLDS();
    // ---- interval 11: d3 ----
    { int rl = (l15 < 7) ? l15 : 7; itile(axT0, 32 + 2 * rl, 48, 32, 8, false); }
    { int rl = (l15 < 3) ? l15 : 3; axT0 = pfx(3 + rl); }   // d2
    BARLDS();
    // ---- interval 12: d2 ----
    { int rl = (l15 < 3) ? l15 : 3; itile(axT0, 48 + 2 * rl, 56, 48, 4, false); }
    { int rl = (l15 < 1) ? l15 : 1; axT0 = pfx(1 + rl); }   // d1
    BARLDS();
    // ---- interval 13: d1 ----
    { int rl = (l15 < 1) ? l15 : 1; itile(axT0, 56 + 2 * rl, 60, 56, 2, false); }
    axT0 = pfx(0);                               // d0 (root)
    BARLDS();
    // ---- interval 14: d0 + out ----
    itile(axT0, 60, 62, 60, 1, true);
}

extern "C" void kernel_launch(void* const* d_in, const int* in_sizes, int n_in,
                              void* d_out, int out_size, void* d_ws, size_t ws_size,
                              hipStream_t stream) {
    const float* feat = (const float*)d_in[0];
    const float* Wiou = (const float*)d_in[1];
    const float* biou = (const float*)d_in[2];
    const float* Uiou = (const float*)d_in[3];
    const float* Wf   = (const float*)d_in[4];
    const float* bfv  = (const float*)d_in[5];
    const float* Uf   = (const float*)d_in[6];
    float* out = (float*)d_out;

    // ws: BgU[131072] BgX[131072] xb16[NN*128] (bf16 shorts), bp5[1280] f32 (~17.3 MB)
    unsigned short* BgU = (unsigned short*)d_ws;
    unsigned short* BgX = BgU + (size_t)131072;
    unsigned short* xb16 = BgX + (size_t)131072;
    float* bp5 = (float*)(xb16 + (size_t)NN * 128);

    pack_b<<<5112, 256, 0, stream>>>(Wiou, biou, Uiou, Wf, bfv, Uf, feat,
                                     BgU, BgX, bp5, xb16);
    forest<<<256, 512, 0, stream>>>(xb16, BgU, BgX, bp5, out);
}